// Round 8
// baseline (313.390 us; speedup 1.0000x reference)
//
#include <hip/hip_runtime.h>

#define NEGV (-1e30f)

// ---------------------------------------------------------------------------
// Kernel 1: fused channel-mean (C=256) + corner mask for all three scales.
// Block: 256 threads = 8 channel-groups (32ch) x 32 position-quads (4 pos).
// Grid: 784 (scale3) + 196 (scale4) + 49 (scale5) = 1029 blocks.
// ---------------------------------------------------------------------------
template <int H, int W, int R0, int R1>
__device__ __forceinline__ void mean_body(int blk, const float* __restrict__ x,
                                          float* __restrict__ scores,
                                          float4* part) {
    constexpr int HW = H * W;
    constexpr int QUADS = HW / 4;
    const int tid = threadIdx.x;
    const int cg = tid >> 5;              // channel group 0..7 (32 channels each)
    const int pl = tid & 31;              // quad lane 0..31
    const int q = blk * 32 + pl;          // global quad task (grid sized exactly)

    const int b = q / QUADS;
    const int quad = q - b * QUADS;
    const float* base = x + (size_t)b * 256 * HW + (size_t)cg * 32 * HW + quad * 4;

    float4 acc = make_float4(0.f, 0.f, 0.f, 0.f);
#pragma unroll 8
    for (int c = 0; c < 32; ++c) {
        const float4 v = *reinterpret_cast<const float4*>(base + (size_t)c * HW);
        acc.x += v.x; acc.y += v.y; acc.z += v.z; acc.w += v.w;
    }
    part[tid] = acc;
    __syncthreads();

    if (tid < 32) {
        float4 s = part[pl];
#pragma unroll
        for (int g = 1; g < 8; ++g) {
            const float4 v = part[g * 32 + pl];
            s.x += v.x; s.y += v.y; s.z += v.z; s.w += v.w;
        }
        const int p0 = quad * 4;
        float r[4] = {s.x, s.y, s.z, s.w};
        float o[4];
#pragma unroll
        for (int e = 0; e < 4; ++e) {
            const int p = p0 + e;
            const int y = p / W;
            const int xx = p - y * W;
            const float val = r[e] * (1.0f / 256.0f);
            const bool in = (y >= R0) && (y < R1) && (xx >= R0) && (xx < R1);
            o[e] = in ? val : 0.0f;
        }
        *reinterpret_cast<float4*>(scores + (size_t)b * HW + p0) =
            make_float4(o[0], o[1], o[2], o[3]);
    }
}

__global__ __launch_bounds__(256) void mean_all_kernel(const float* __restrict__ x3,
                                                       const float* __restrict__ x4,
                                                       const float* __restrict__ x5,
                                                       float* __restrict__ sc3,
                                                       float* __restrict__ sc4,
                                                       float* __restrict__ sc5) {
    __shared__ float4 part[256];
    const int bid = blockIdx.x;
    if (bid < 784) {
        mean_body<56, 56, 5, 50>(bid, x3, sc3, part);
    } else if (bid < 980) {
        mean_body<28, 28, 2, 25>(bid - 784, x4, sc4, part);
    } else {
        mean_body<14, 14, 1, 12>(bid - 980, x5, sc5, part);
    }
}

// ---------------------------------------------------------------------------
// Kernel 2: fused NMS (wave-synchronous, zero barriers in top-k loop)
//           + per-batch union bounds (4 ints).
// One block per batch (32 blocks x 256 threads). Wave 0: scale3, wave 1:
// scale4, wave 2: scale5, wave 3 idle. Scores in registers; argmax via
// 64-wide shfl butterfly (strict > + min-index == jnp.argmax first-occurrence).
// ---------------------------------------------------------------------------
template <int HW, int W, int TOPK, int ISTRIDE, int ISIZE, int BOXOFF>
__device__ __forceinline__ void nms_wave(int b, const float* __restrict__ sc,
                                         float* __restrict__ obox,
                                         float (*sbox)[4]) {
    constexpr int NPT = (HW + 63) / 64;
    const int lane = threadIdx.x & 63;

    float s[NPT];
    float sum = 0.f;
#pragma unroll
    for (int i = 0; i < NPT; ++i) {
        const int j = lane + 64 * i;
        const float v = (j < HW) ? sc[j] : NEGV;
        s[i] = v;
        if (j < HW) sum += v;
    }
#pragma unroll
    for (int off = 32; off > 0; off >>= 1) sum += __shfl_down(sum, off, 64);
    const float mean = __shfl(sum, 0, 64) / (float)HW;

#pragma unroll
    for (int i = 0; i < NPT; ++i) s[i] = (s[i] > mean) ? s[i] : NEGV;

    constexpr float half = 0.5f * (float)ISIZE;
    constexpr float area2 = 2.0f * (float)ISIZE * (float)ISIZE;

    for (int k = 0; k < TOPK; ++k) {
        float bv = -3.0e38f;
        int bi = 0x7fffffff;
#pragma unroll
        for (int i = 0; i < NPT; ++i) {
            if (s[i] > bv) { bv = s[i]; bi = lane + 64 * i; }
        }
#pragma unroll
        for (int off = 32; off > 0; off >>= 1) {
            const float ov = __shfl_down(bv, off, 64);
            const int oi = __shfl_down(bi, off, 64);
            if (ov > bv || (ov == bv && oi < bi)) { bv = ov; bi = oi; }
        }
        const int wi = __shfl(bi, 0, 64);

        const int gy = wi / W;
        const int gx = wi - gy * W;
        const float bx1 = (float)gx * (float)ISTRIDE - half;
        const float by1 = (float)gy * (float)ISTRIDE - half;
        const float bx2 = (float)gx * (float)ISTRIDE + half;
        const float by2 = (float)gy * (float)ISTRIDE + half;

        if (lane == 0) {
            const float c0 = fmaxf(bx1, 0.f);
            const float c1 = fmaxf(by1, 0.f);
            const float c2 = fminf(bx2, 447.f);
            const float c3 = fminf(by2, 447.f);
            float* r = obox + k * 5;
            r[0] = (float)b;
            r[1] = c0; r[2] = c1; r[3] = c2; r[4] = c3;
            sbox[BOXOFF + k][0] = c0;
            sbox[BOXOFF + k][1] = c1;
            sbox[BOXOFF + k][2] = c2;
            sbox[BOXOFF + k][3] = c3;
        }

        // Suppress: IoU on raw (unclamped) anchors, threshold 0.05.
#pragma unroll
        for (int i = 0; i < NPT; ++i) {
            const int j = lane + 64 * i;
            const int ay = j / W;
            const int ax = j - ay * W;
            const float acx = (float)ax * (float)ISTRIDE;
            const float acy = (float)ay * (float)ISTRIDE;
            const float ix1 = fmaxf(bx1, acx - half);
            const float iy1 = fmaxf(by1, acy - half);
            const float ix2 = fminf(bx2, acx + half);
            const float iy2 = fminf(by2, acy + half);
            const float inter = fmaxf(ix2 - ix1, 0.f) * fmaxf(iy2 - iy1, 0.f);
            const float iou = inter / (area2 - inter);
            if (iou > 0.05f || j == wi) s[i] = NEGV;
        }
    }
}

__global__ __launch_bounds__(256) void nms_bounds_kernel(const float* __restrict__ sc3,
                                                         const float* __restrict__ sc4,
                                                         const float* __restrict__ sc5,
                                                         float* __restrict__ out,
                                                         int* __restrict__ bnds) {
    __shared__ float sbox[9][4];

    const int b = blockIdx.x;
    const int tid = threadIdx.x;
    const int wave = tid >> 6;

    if (wave == 0) {
        nms_wave<3136, 56, 5, 8, 64, 0>(b, sc3 + (size_t)b * 3136, out + (size_t)b * 25, sbox);
    } else if (wave == 1) {
        nms_wave<784, 28, 3, 16, 128, 5>(b, sc4 + (size_t)b * 784, out + 800 + (size_t)b * 15, sbox);
    } else if (wave == 2) {
        nms_wave<196, 14, 1, 32, 256, 8>(b, sc5 + (size_t)b * 196, out + 1280 + (size_t)b * 5, sbox);
    }
    __syncthreads();

    if (tid == 0) {
        float x1 = 3.0e38f, y1 = 3.0e38f, x2 = -3.0e38f, y2 = -3.0e38f;
#pragma unroll
        for (int i = 0; i < 9; ++i) {
            x1 = fminf(x1, sbox[i][0]);
            y1 = fminf(y1, sbox[i][1]);
            x2 = fmaxf(x2, sbox[i][2]);
            y2 = fmaxf(y2, sbox[i][3]);
        }
        const int x1i = (int)floorf(x1 * 0.125f);
        const int y1i = (int)floorf(y1 * 0.125f);
        const int x2i = (int)floorf(x2 * 0.125f);
        const int y2i = (int)floorf(y2 * 0.125f);
        bnds[b * 4 + 0] = x1i;
        bnds[b * 4 + 1] = y1i;
        bnds[b * 4 + 2] = x2i - x1i;  // cw
        bnds[b * 4 + 3] = y2i - y1i;  // ch
    }
}

// ---------------------------------------------------------------------------
// Kernel 3: bilinear crop-resize, direct global gathers (each 12.5 KB plane
// is L1-resident, so gathers are L1 hits — LDS staging measured slower, R6).
// 2048 blocks x 448 threads; each block does 4 consecutive channel planes of
// one batch (64 blocks/batch). Axis tables computed in-block from bnds into
// LDS. xx = tid%56 loop-invariant; y = tid/56 + 8*i; stores block-contiguous.
// ---------------------------------------------------------------------------
__global__ __launch_bounds__(448) void crop_kernel(const float* __restrict__ x2,
                                                   const int* __restrict__ bnds,
                                                   float* __restrict__ outc) {
    __shared__ int sy0[56], sy1[56];
    __shared__ float sfy[56];
    __shared__ int sx0[56], sx1[56];
    __shared__ float sfx[56];

    const int blk = blockIdx.x;      // [0, 2048)
    const int b = blk >> 6;          // batch (64 blocks per batch)
    const int c0 = (blk & 63) * 4;   // first of 4 channels
    const int tid = threadIdx.x;

    const int x1i = bnds[b * 4 + 0];
    const int y1i = bnds[b * 4 + 1];
    const int cw = bnds[b * 4 + 2];
    const int ch = bnds[b * 4 + 3];

    // Compute bilinear axis tables (exactly matching reference float math).
    if (tid < 112) {
        const int axis = tid / 56;   // 0: y, 1: x
        const int o = tid - axis * 56;
        if (axis == 0) {
            const float s = fmaxf(((float)o + 0.5f) * ((float)ch / 56.0f) - 0.5f, 0.f);
            const int i0 = (int)s;
            const int i1 = min(i0 + 1, ch - 1);
            sy0[o] = (y1i + i0) * 56;   // global row offsets
            sy1[o] = (y1i + i1) * 56;
            sfy[o] = s - (float)i0;
        } else {
            const float s = fmaxf(((float)o + 0.5f) * ((float)cw / 56.0f) - 0.5f, 0.f);
            const int i0 = (int)s;
            const int i1 = min(i0 + 1, cw - 1);
            sx0[o] = x1i + i0;          // global columns
            sx1[o] = x1i + i1;
            sfx[o] = s - (float)i0;
        }
    }
    __syncthreads();

    const int y0 = tid / 56;       // 0..7
    const int xx = tid - y0 * 56;  // 0..55, loop-invariant
    const int gx0 = sx0[xx];
    const int gx1 = sx1[xx];
    const float fx = sfx[xx];

    const size_t base = (size_t)(b * 256 + c0) * 3136;
    for (int p = 0; p < 4; ++p) {
        const float* plane = x2 + base + (size_t)p * 3136;
        float* op = outc + base + (size_t)p * 3136;
#pragma unroll
        for (int i = 0; i < 7; ++i) {
            const int y = y0 + 8 * i;
            const int r0 = sy0[y];
            const int r1 = sy1[y];
            const float fy = sfy[y];
            const float v00 = plane[r0 + gx0];
            const float v01 = plane[r0 + gx1];
            const float v10 = plane[r1 + gx0];
            const float v11 = plane[r1 + gx1];
            const float top = v00 + fx * (v01 - v00);
            const float bot = v10 + fx * (v11 - v10);
            op[tid + 448 * i] = top + fy * (bot - top);
        }
    }
}

// ---------------------------------------------------------------------------
extern "C" void kernel_launch(void* const* d_in, const int* in_sizes, int n_in,
                              void* d_out, int out_size, void* d_ws, size_t ws_size,
                              hipStream_t stream) {
    const float* x2 = (const float*)d_in[0];
    const float* x3 = (const float*)d_in[1];
    const float* x4 = (const float*)d_in[2];
    const float* x5 = (const float*)d_in[3];
    float* out = (float*)d_out;

    float* sc3 = (float*)d_ws;                 // 32*3136
    float* sc4 = sc3 + 32 * 3136;              // 32*784
    float* sc5 = sc4 + 32 * 784;               // 32*196
    int* bnds = (int*)(sc5 + 32 * 196);        // 32*4 ints (x1i, y1i, cw, ch)

    mean_all_kernel<<<1029, 256, 0, stream>>>(x3, x4, x5, sc3, sc4, sc5);
    nms_bounds_kernel<<<32, 256, 0, stream>>>(sc3, sc4, sc5, out, bnds);
    crop_kernel<<<2048, 448, 0, stream>>>(x2, bnds, out + 1440);
}

// Round 9
// 293.432 us; speedup vs baseline: 1.0680x; 1.0680x over previous
//
#include <hip/hip_runtime.h>

#define NEGV (-1e30f)

// ---------------------------------------------------------------------------
// Kernel 1: fused channel-mean (C=256) + corner mask for all three scales.
// Block: 256 threads = 8 channel-groups (32ch) x 32 position-quads (4 pos).
// Grid: 784 (scale3) + 196 (scale4) + 49 (scale5) = 1029 blocks.
// ---------------------------------------------------------------------------
template <int H, int W, int R0, int R1>
__device__ __forceinline__ void mean_body(int blk, const float* __restrict__ x,
                                          float* __restrict__ scores,
                                          float4* part) {
    constexpr int HW = H * W;
    constexpr int QUADS = HW / 4;
    const int tid = threadIdx.x;
    const int cg = tid >> 5;              // channel group 0..7 (32 channels each)
    const int pl = tid & 31;              // quad lane 0..31
    const int q = blk * 32 + pl;          // global quad task (grid sized exactly)

    const int b = q / QUADS;
    const int quad = q - b * QUADS;
    const float* base = x + (size_t)b * 256 * HW + (size_t)cg * 32 * HW + quad * 4;

    float4 acc = make_float4(0.f, 0.f, 0.f, 0.f);
#pragma unroll 8
    for (int c = 0; c < 32; ++c) {
        const float4 v = *reinterpret_cast<const float4*>(base + (size_t)c * HW);
        acc.x += v.x; acc.y += v.y; acc.z += v.z; acc.w += v.w;
    }
    part[tid] = acc;
    __syncthreads();

    if (tid < 32) {
        float4 s = part[pl];
#pragma unroll
        for (int g = 1; g < 8; ++g) {
            const float4 v = part[g * 32 + pl];
            s.x += v.x; s.y += v.y; s.z += v.z; s.w += v.w;
        }
        const int p0 = quad * 4;
        float r[4] = {s.x, s.y, s.z, s.w};
        float o[4];
#pragma unroll
        for (int e = 0; e < 4; ++e) {
            const int p = p0 + e;
            const int y = p / W;
            const int xx = p - y * W;
            const float val = r[e] * (1.0f / 256.0f);
            const bool in = (y >= R0) && (y < R1) && (xx >= R0) && (xx < R1);
            o[e] = in ? val : 0.0f;
        }
        *reinterpret_cast<float4*>(scores + (size_t)b * HW + p0) =
            make_float4(o[0], o[1], o[2], o[3]);
    }
}

__global__ __launch_bounds__(256) void mean_all_kernel(const float* __restrict__ x3,
                                                       const float* __restrict__ x4,
                                                       const float* __restrict__ x5,
                                                       float* __restrict__ sc3,
                                                       float* __restrict__ sc4,
                                                       float* __restrict__ sc5) {
    __shared__ float4 part[256];
    const int bid = blockIdx.x;
    if (bid < 784) {
        mean_body<56, 56, 5, 50>(bid, x3, sc3, part);
    } else if (bid < 980) {
        mean_body<28, 28, 2, 25>(bid - 784, x4, sc4, part);
    } else {
        mean_body<14, 14, 1, 12>(bid - 980, x5, sc5, part);
    }
}

// ---------------------------------------------------------------------------
// Kernel 2: fused NMS (wave-synchronous, zero barriers in top-k loop)
//           + per-batch union bounds (4 ints).
// One block per batch (32 blocks x 256 threads). Wave 0: scale3, wave 1:
// scale4, wave 2: scale5, wave 3 idle. Scores in registers; argmax via
// 64-wide shfl butterfly (strict > + min-index == jnp.argmax first-occurrence).
// ---------------------------------------------------------------------------
template <int HW, int W, int TOPK, int ISTRIDE, int ISIZE, int BOXOFF>
__device__ __forceinline__ void nms_wave(int b, const float* __restrict__ sc,
                                         float* __restrict__ obox,
                                         float (*sbox)[4]) {
    constexpr int NPT = (HW + 63) / 64;
    const int lane = threadIdx.x & 63;

    float s[NPT];
    float sum = 0.f;
#pragma unroll
    for (int i = 0; i < NPT; ++i) {
        const int j = lane + 64 * i;
        const float v = (j < HW) ? sc[j] : NEGV;
        s[i] = v;
        if (j < HW) sum += v;
    }
#pragma unroll
    for (int off = 32; off > 0; off >>= 1) sum += __shfl_down(sum, off, 64);
    const float mean = __shfl(sum, 0, 64) / (float)HW;

#pragma unroll
    for (int i = 0; i < NPT; ++i) s[i] = (s[i] > mean) ? s[i] : NEGV;

    constexpr float half = 0.5f * (float)ISIZE;
    constexpr float area2 = 2.0f * (float)ISIZE * (float)ISIZE;

    for (int k = 0; k < TOPK; ++k) {
        float bv = -3.0e38f;
        int bi = 0x7fffffff;
#pragma unroll
        for (int i = 0; i < NPT; ++i) {
            if (s[i] > bv) { bv = s[i]; bi = lane + 64 * i; }
        }
#pragma unroll
        for (int off = 32; off > 0; off >>= 1) {
            const float ov = __shfl_down(bv, off, 64);
            const int oi = __shfl_down(bi, off, 64);
            if (ov > bv || (ov == bv && oi < bi)) { bv = ov; bi = oi; }
        }
        const int wi = __shfl(bi, 0, 64);

        const int gy = wi / W;
        const int gx = wi - gy * W;
        const float bx1 = (float)gx * (float)ISTRIDE - half;
        const float by1 = (float)gy * (float)ISTRIDE - half;
        const float bx2 = (float)gx * (float)ISTRIDE + half;
        const float by2 = (float)gy * (float)ISTRIDE + half;

        if (lane == 0) {
            const float c0 = fmaxf(bx1, 0.f);
            const float c1 = fmaxf(by1, 0.f);
            const float c2 = fminf(bx2, 447.f);
            const float c3 = fminf(by2, 447.f);
            float* r = obox + k * 5;
            r[0] = (float)b;
            r[1] = c0; r[2] = c1; r[3] = c2; r[4] = c3;
            sbox[BOXOFF + k][0] = c0;
            sbox[BOXOFF + k][1] = c1;
            sbox[BOXOFF + k][2] = c2;
            sbox[BOXOFF + k][3] = c3;
        }

        // Suppress: IoU on raw (unclamped) anchors, threshold 0.05.
#pragma unroll
        for (int i = 0; i < NPT; ++i) {
            const int j = lane + 64 * i;
            const int ay = j / W;
            const int ax = j - ay * W;
            const float acx = (float)ax * (float)ISTRIDE;
            const float acy = (float)ay * (float)ISTRIDE;
            const float ix1 = fmaxf(bx1, acx - half);
            const float iy1 = fmaxf(by1, acy - half);
            const float ix2 = fminf(bx2, acx + half);
            const float iy2 = fminf(by2, acy + half);
            const float inter = fmaxf(ix2 - ix1, 0.f) * fmaxf(iy2 - iy1, 0.f);
            const float iou = inter / (area2 - inter);
            if (iou > 0.05f || j == wi) s[i] = NEGV;
        }
    }
}

__global__ __launch_bounds__(256) void nms_bounds_kernel(const float* __restrict__ sc3,
                                                         const float* __restrict__ sc4,
                                                         const float* __restrict__ sc5,
                                                         float* __restrict__ out,
                                                         int* __restrict__ bnds) {
    __shared__ float sbox[9][4];

    const int b = blockIdx.x;
    const int tid = threadIdx.x;
    const int wave = tid >> 6;

    if (wave == 0) {
        nms_wave<3136, 56, 5, 8, 64, 0>(b, sc3 + (size_t)b * 3136, out + (size_t)b * 25, sbox);
    } else if (wave == 1) {
        nms_wave<784, 28, 3, 16, 128, 5>(b, sc4 + (size_t)b * 784, out + 800 + (size_t)b * 15, sbox);
    } else if (wave == 2) {
        nms_wave<196, 14, 1, 32, 256, 8>(b, sc5 + (size_t)b * 196, out + 1280 + (size_t)b * 5, sbox);
    }
    __syncthreads();

    if (tid == 0) {
        float x1 = 3.0e38f, y1 = 3.0e38f, x2 = -3.0e38f, y2 = -3.0e38f;
#pragma unroll
        for (int i = 0; i < 9; ++i) {
            x1 = fminf(x1, sbox[i][0]);
            y1 = fminf(y1, sbox[i][1]);
            x2 = fmaxf(x2, sbox[i][2]);
            y2 = fmaxf(y2, sbox[i][3]);
        }
        const int x1i = (int)floorf(x1 * 0.125f);
        const int y1i = (int)floorf(y1 * 0.125f);
        const int x2i = (int)floorf(x2 * 0.125f);
        const int y2i = (int)floorf(y2 * 0.125f);
        bnds[b * 4 + 0] = x1i;
        bnds[b * 4 + 1] = y1i;
        bnds[b * 4 + 2] = x2i - x1i;  // cw
        bnds[b * 4 + 3] = y2i - y1i;  // ch
    }
}

// ---------------------------------------------------------------------------
// Kernel 3: bilinear crop-resize. ONE plane per block, 8192 blocks x 448
// threads — the measured-best structure (R3: <=59.4us, occupancy ~73%).
// Latency-bound gathers need max resident waves; 4-planes/block @2048 blocks
// measured 67us at 33% occupancy (R8) — do not repeat.
// Axis tables computed in-block from bnds (112 threads, ~10 VALU each;
// eliminates the R3 global table round-trip). Gathers go direct to global:
// each 12.5KB plane is L1-resident (LDS staging measured slower, R6).
// xx = tid%56 loop-invariant; y = tid/56 + 8*i; stores block-contiguous.
// ---------------------------------------------------------------------------
__global__ __launch_bounds__(448) void crop_kernel(const float* __restrict__ x2,
                                                   const int* __restrict__ bnds,
                                                   float* __restrict__ outc) {
    __shared__ int sy0[56], sy1[56];
    __shared__ float sfy[56];
    __shared__ int sx0[56], sx1[56];
    __shared__ float sfx[56];

    const int bc = blockIdx.x;       // b*256 + c
    const int b = bc >> 8;
    const int tid = threadIdx.x;

    const int x1i = bnds[b * 4 + 0];
    const int y1i = bnds[b * 4 + 1];
    const int cw = bnds[b * 4 + 2];
    const int ch = bnds[b * 4 + 3];

    // Compute bilinear axis tables (exactly matching reference float math).
    if (tid < 112) {
        const int axis = tid / 56;   // 0: y, 1: x
        const int o = tid - axis * 56;
        if (axis == 0) {
            const float s = fmaxf(((float)o + 0.5f) * ((float)ch / 56.0f) - 0.5f, 0.f);
            const int i0 = (int)s;
            const int i1 = min(i0 + 1, ch - 1);
            sy0[o] = (y1i + i0) * 56;   // global row offsets
            sy1[o] = (y1i + i1) * 56;
            sfy[o] = s - (float)i0;
        } else {
            const float s = fmaxf(((float)o + 0.5f) * ((float)cw / 56.0f) - 0.5f, 0.f);
            const int i0 = (int)s;
            const int i1 = min(i0 + 1, cw - 1);
            sx0[o] = x1i + i0;          // global columns
            sx1[o] = x1i + i1;
            sfx[o] = s - (float)i0;
        }
    }
    __syncthreads();

    const int y0 = tid / 56;       // 0..7
    const int xx = tid - y0 * 56;  // 0..55, loop-invariant
    const int gx0 = sx0[xx];
    const int gx1 = sx1[xx];
    const float fx = sfx[xx];

    const float* plane = x2 + (size_t)bc * 3136;
    float* op = outc + (size_t)bc * 3136;

#pragma unroll
    for (int i = 0; i < 7; ++i) {
        const int y = y0 + 8 * i;
        const int r0 = sy0[y];
        const int r1 = sy1[y];
        const float fy = sfy[y];
        const float v00 = plane[r0 + gx0];
        const float v01 = plane[r0 + gx1];
        const float v10 = plane[r1 + gx0];
        const float v11 = plane[r1 + gx1];
        const float top = v00 + fx * (v01 - v00);
        const float bot = v10 + fx * (v11 - v10);
        op[tid + 448 * i] = top + fy * (bot - top);
    }
}

// ---------------------------------------------------------------------------
extern "C" void kernel_launch(void* const* d_in, const int* in_sizes, int n_in,
                              void* d_out, int out_size, void* d_ws, size_t ws_size,
                              hipStream_t stream) {
    const float* x2 = (const float*)d_in[0];
    const float* x3 = (const float*)d_in[1];
    const float* x4 = (const float*)d_in[2];
    const float* x5 = (const float*)d_in[3];
    float* out = (float*)d_out;

    float* sc3 = (float*)d_ws;                 // 32*3136
    float* sc4 = sc3 + 32 * 3136;              // 32*784
    float* sc5 = sc4 + 32 * 784;               // 32*196
    int* bnds = (int*)(sc5 + 32 * 196);        // 32*4 ints (x1i, y1i, cw, ch)

    mean_all_kernel<<<1029, 256, 0, stream>>>(x3, x4, x5, sc3, sc4, sc5);
    nms_bounds_kernel<<<32, 256, 0, stream>>>(sc3, sc4, sc5, out, bnds);
    crop_kernel<<<8192, 448, 0, stream>>>(x2, bnds, out + 1440);
}